// Round 5
// baseline (431.438 us; speedup 1.0000x reference)
//
#include <hip/hip_runtime.h>

typedef __attribute__((ext_vector_type(8))) unsigned short ushort8_t;
typedef __attribute__((ext_vector_type(8))) __bf16 bf16x8;
typedef __attribute__((ext_vector_type(16))) float f32x16;
typedef __attribute__((ext_vector_type(4))) float f32x4;

#define NSEG 2176   // 32 styles * 68 comps
#define NITEM 1536  // B*3

__device__ inline unsigned short f2bf(float f) {
    unsigned int b = __builtin_bit_cast(unsigned int, f);
    b += 0x7FFFu + ((b >> 16) & 1u);   // round-to-nearest-even
    return (unsigned short)(b >> 16);
}
__device__ inline float bf2f(unsigned short h) {
    unsigned int b = ((unsigned int)h) << 16;
    return __builtin_bit_cast(float, b);
}

// ---------------- Kernel AW: block 1728 = CSR build; blocks 0..1727 = weight repack ----------------
__global__ __launch_bounds__(256) void kAW(const int* __restrict__ style,
                                           const int* __restrict__ cids,
                                           const float* __restrict__ w1,
                                           const float* __restrict__ w2,
                                           const float* __restrict__ w3,
                                           unsigned short* __restrict__ Bp,
                                           int* __restrict__ list_g,
                                           int* __restrict__ segstart_g, int* __restrict__ segcnt_g,
                                           int* __restrict__ segkey_g, int* __restrict__ nseg_g) {
    const int tid = threadIdx.x;
    if (blockIdx.x < 1728) {
        // weight repack -> Bp[kb][co][8] bf16, k=(tap,ci)
        const int t = blockIdx.x * 256 + tid;
        const int l = t / 147456;
        const int o = t - l * 147456;
        const int slot = o & 7;
        const int co = (o >> 3) & 127;
        const int kb = o >> 10;
        const int tap = kb >> 4;
        const int ci = ((kb & 15) << 3) | slot;
        const float* w = (l == 0) ? w1 : (l == 1) ? w2 : w3;
        Bp[t] = f2bf(w[(co * 128 + ci) * 9 + tap]);
        return;
    }
    // ---- CSR build (single block) ----
    __shared__ int cnt[NSEG];
    __shared__ int sstart[NSEG];
    __shared__ int partial[256];
    __shared__ int nseg_sh;
    const int lane = tid & 63;
    const int wid = tid >> 6;
    for (int s = tid; s < NSEG; s += 256) cnt[s] = 0;
    if (tid == 0) nseg_sh = 0;
    __syncthreads();
    int myrank[6], mykey[6];
    #pragma unroll
    for (int k = 0; k < 6; ++k) {
        const int i = k * 256 + tid;
        const int b = i / 3, j = i - b * 3;
        const int off = (j == 0) ? 0 : (j == 1) ? 19 : 40;
        const int a = cids[i] + off;
        const int key = style[b] * 68 + a;
        mykey[k] = key;
        myrank[k] = atomicAdd(&cnt[key], 1);
    }
    __syncthreads();
    const int base = tid * 9;
    int ssum = 0;
    for (int q = 0; q < 9; ++q) { int s = base + q; if (s < NSEG) ssum += cnt[s]; }
    partial[tid] = ssum;
    __syncthreads();
    if (wid == 0) {
        int s0 = partial[lane * 4 + 0], s1 = partial[lane * 4 + 1];
        int s2 = partial[lane * 4 + 2], s3 = partial[lane * 4 + 3];
        const int loc = s0 + s1 + s2 + s3;
        int pre = loc;
        #pragma unroll
        for (int d = 1; d < 64; d <<= 1) {
            const int o = __shfl_up(pre, d);
            if (lane >= d) pre += o;
        }
        pre -= loc;  // exclusive
        partial[lane * 4 + 0] = pre;
        partial[lane * 4 + 1] = pre + s0;
        partial[lane * 4 + 2] = pre + s0 + s1;
        partial[lane * 4 + 3] = pre + s0 + s1 + s2;
    }
    __syncthreads();
    int run = partial[tid];
    for (int q = 0; q < 9; ++q) {
        int s = base + q;
        if (s < NSEG) {
            sstart[s] = run; segstart_g[s] = run; segcnt_g[s] = cnt[s];
            if (cnt[s] > 0) { const int ix = atomicAdd(&nseg_sh, 1); segkey_g[ix] = s; }
            run += cnt[s];
        }
    }
    __syncthreads();
    if (tid == 0) nseg_g[0] = nseg_sh;
    #pragma unroll
    for (int k = 0; k < 6; ++k) {
        const int i = k * 256 + tid;
        list_g[sstart[mykey[k]] + myrank[k]] = i;
    }
}

// ------------- Kernel CF: fused 3-layer conv+relu, one block per comp image -------------
// 1024 threads = 16 waves = 4 waves/SIMD. Single 64KB LDS activation buffer,
// layout [m=h*16+w][ci] bf16, byte ^= (m&15)<<4 swizzle.
// Wave wid: wm=wid>>1 (M-tile, 32 rows), wn=wid&1 (N-half); computes 1x2 tiles, acc[2].
// mfma_f32_32x32x16_bf16: A row=l&31, k=(l>>5)*8+j ; B col=l&31 same k ;
// D col=l&31, row=(r&3)+8*(r>>2)+4*(l>>5)
__global__ __launch_bounds__(1024) void kConvF(const float* __restrict__ bias_in,
                                               const unsigned short* __restrict__ Bp,
                                               const float* __restrict__ b1,
                                               const float* __restrict__ b2,
                                               const float* __restrict__ b3,
                                               unsigned short* __restrict__ pbu_out) {
    __shared__ char lds[65536];
    const int tid = threadIdx.x;
    const int u = blockIdx.x;

    // Stage layer-0 input: bias[u] is [C][256]; -> [m][ci] bf16 swizzled.
    // thread: channels 4*c4..4*c4+3, rows mbase+32*it  (conflict-free 8B LDS writes)
    {
        const float* src = bias_in + (size_t)u * 32768;
        const int c4 = tid & 31;
        const int mbase = tid >> 5;
        #pragma unroll
        for (int it = 0; it < 8; ++it) {
            const int m = mbase + 32 * it;
            ushort4 pk;
            pk.x = f2bf(src[(c4 * 4 + 0) * 256 + m]);
            pk.y = f2bf(src[(c4 * 4 + 1) * 256 + m]);
            pk.z = f2bf(src[(c4 * 4 + 2) * 256 + m]);
            pk.w = f2bf(src[(c4 * 4 + 3) * 256 + m]);
            const int off = (m * 256 + c4 * 8) ^ ((m & 15) << 4);
            *(ushort4*)(lds + off) = pk;
        }
    }
    __syncthreads();

    const int lane = tid & 63;
    const int wid = tid >> 6;
    const int wm = wid >> 1;   // 0..7  M-tile
    const int wn = wid & 1;    // 0..1  N-half (2 tiles)
    const int lrow = lane & 31;
    const int lhi = lane >> 5;

    for (int layer = 0; layer < 3; ++layer) {
        const unsigned short* Bpl = Bp + (size_t)layer * 147456;
        const float* bv = (layer == 0) ? b1 : (layer == 1) ? b2 : b3;

        f32x16 acc[2] = {};

        #pragma unroll 2
        for (int kk = 0; kk < 72; ++kk) {
            const int tap = kk >> 3;
            const int t3 = tap / 3;
            const int oh = t3 - 1;
            const int ow = (tap - t3 * 3) - 1;
            const int ci0 = (kk & 7) * 16 + lhi * 8;
            const int kb = kk * 2 + lhi;

            bf16x8 bfrag[2];
            #pragma unroll
            for (int t2 = 0; t2 < 2; ++t2) {
                const int co = (wn * 2 + t2) * 32 + lrow;
                bfrag[t2] = __builtin_bit_cast(bf16x8,
                    *(const ushort8_t*)(Bpl + ((size_t)(kb * 128 + co)) * 8));
            }
            const int m = wm * 32 + lrow;
            const int h = (m >> 4) + oh;
            const int w = (m & 15) + ow;
            ushort8_t v = {0, 0, 0, 0, 0, 0, 0, 0};
            if ((unsigned)h < 16u && (unsigned)w < 16u) {
                const int m2 = h * 16 + w;
                const int off = (m2 * 256 + ci0 * 2) ^ ((m2 & 15) << 4);
                v = *(const ushort8_t*)(lds + off);
            }
            const bf16x8 afrag = __builtin_bit_cast(bf16x8, v);
            #pragma unroll
            for (int t2 = 0; t2 < 2; ++t2)
                acc[t2] = __builtin_amdgcn_mfma_f32_32x32x16_bf16(
                    afrag, bfrag[t2], acc[t2], 0, 0, 0);
        }

        if (layer < 2) {
            // bias+relu+bf16 into registers (static indices), then in-place LDS rewrite
            unsigned short pk[2][16];
            #pragma unroll
            for (int t2 = 0; t2 < 2; ++t2) {
                const float bb = bv[(wn * 2 + t2) * 32 + lrow];
                #pragma unroll
                for (int r = 0; r < 16; ++r)
                    pk[t2][r] = f2bf(fmaxf(acc[t2][r] + bb, 0.0f));
            }
            __syncthreads();   // all waves done reading current activation
            #pragma unroll
            for (int t2 = 0; t2 < 2; ++t2) {
                const int co = (wn * 2 + t2) * 32 + lrow;
                #pragma unroll
                for (int r = 0; r < 16; ++r) {
                    const int m = wm * 32 + (r & 3) + 8 * (r >> 2) + 4 * lhi;
                    const int off = (m * 256 + co * 2) ^ ((m & 15) << 4);
                    *(unsigned short*)(lds + off) = pk[t2][r];
                }
            }
            __syncthreads();   // next layer may read
        } else {
            // final layer: pbu in [u][co][m] bf16, packed 4-wide along m
            #pragma unroll
            for (int t2 = 0; t2 < 2; ++t2) {
                const int co = (wn * 2 + t2) * 32 + lrow;
                const float bb = bv[co];
                #pragma unroll
                for (int rq = 0; rq < 4; ++rq) {
                    const int m0 = wm * 32 + 8 * rq + 4 * lhi;
                    ushort4 pkv;
                    pkv.x = f2bf(fmaxf(acc[t2][rq * 4 + 0] + bb, 0.0f));
                    pkv.y = f2bf(fmaxf(acc[t2][rq * 4 + 1] + bb, 0.0f));
                    pkv.z = f2bf(fmaxf(acc[t2][rq * 4 + 2] + bb, 0.0f));
                    pkv.w = f2bf(fmaxf(acc[t2][rq * 4 + 3] + bb, 0.0f));
                    *(ushort4*)(pbu_out + (size_t)u * 32768 + co * 256 + m0) = pkv;
                }
            }
        }
    }
}

// ------------- Kernel B: per-active-segment mean + pbu add + broadcast -------------
__global__ __launch_bounds__(256) void kB(const float* __restrict__ feats,
                                          const unsigned short* __restrict__ pbu,
                                          const int* __restrict__ list_g,
                                          const int* __restrict__ segkey_g,
                                          const int* __restrict__ segstart_g,
                                          const int* __restrict__ segcnt_g,
                                          const int* __restrict__ nseg_g,
                                          float* __restrict__ out) {
    const int sy = blockIdx.y;
    if (sy >= nseg_g[0]) return;
    const int s = segkey_g[sy];
    const int st = segstart_g[s];
    const int n = segcnt_g[s];
    const int a = s % 68;                         // all items in segment share addr
    const int e = blockIdx.x * 1024 + threadIdx.x * 4;

    f32x4 acc = {0.f, 0.f, 0.f, 0.f};
    for (int t = 0; t < n; ++t) {
        const int j = list_g[st + t];
        const f32x4 v = __builtin_nontemporal_load(
            (const f32x4*)(feats + (size_t)j * 32768 + e));
        acc += v;
    }
    const float inv = 1.0f / (float)n;
    const ushort4 p = *(const ushort4*)(pbu + (size_t)a * 32768 + e);
    f32x4 o;
    o.x = acc.x * inv + bf2f(p.x);
    o.y = acc.y * inv + bf2f(p.y);
    o.z = acc.z * inv + bf2f(p.z);
    o.w = acc.w * inv + bf2f(p.w);
    for (int t = 0; t < n; ++t) {
        const int j = list_g[st + t];
        __builtin_nontemporal_store(o, (f32x4*)(out + (size_t)j * 32768 + e));
    }
}

extern "C" void kernel_launch(void* const* d_in, const int* in_sizes, int n_in,
                              void* d_out, int out_size, void* d_ws, size_t ws_size,
                              hipStream_t stream) {
    const int* style   = (const int*)d_in[0];
    const int* cids    = (const int*)d_in[1];
    const float* feats = (const float*)d_in[2];
    const float* bias  = (const float*)d_in[3];
    const float* w1    = (const float*)d_in[4];
    const float* b1    = (const float*)d_in[5];
    const float* w2    = (const float*)d_in[6];
    const float* b2    = (const float*)d_in[7];
    const float* w3    = (const float*)d_in[8];
    const float* b3    = (const float*)d_in[9];
    float* out = (float*)d_out;
    char* ws = (char*)d_ws;

    int* list_g     = (int*)(ws + 0);        // 1536 ints
    int* segstart_g = (int*)(ws + 8192);     // 2176 ints
    int* segcnt_g   = (int*)(ws + 16896);    // 2176 ints
    int* segkey_g   = (int*)(ws + 25600);    // 2176 ints
    int* nseg_g     = (int*)(ws + 34304);    // 1 int
    unsigned short* Bp  = (unsigned short*)(ws + 65536);     // 3*147456 bf16
    unsigned short* pbu = (unsigned short*)(ws + 1048576);   // 68*32768 bf16 = 4.25MB

    hipLaunchKernelGGL(kAW, dim3(1729), dim3(256), 0, stream,
                       style, cids, w1, w2, w3, Bp,
                       list_g, segstart_g, segcnt_g, segkey_g, nseg_g);
    hipLaunchKernelGGL(kConvF, dim3(68), dim3(1024), 0, stream,
                       bias, Bp, b1, b2, b3, pbu);
    hipLaunchKernelGGL(kB, dim3(32, NITEM), dim3(256), 0, stream,
                       feats, pbu, list_g, segkey_g, segstart_g, segcnt_g, nseg_g, out);
}